// Round 18
// baseline (116.973 us; speedup 1.0000x reference)
//
#include <hip/hip_runtime.h>
#include <hip/hip_bf16.h>
#include <math.h>

#define DEVFN __device__ __forceinline__

typedef __attribute__((ext_vector_type(8))) __bf16 bf16x8;
typedef __attribute__((ext_vector_type(8))) short s16x8;
typedef __attribute__((ext_vector_type(4))) float f32x4;
typedef __attribute__((ext_vector_type(4))) unsigned int u32x4;

constexpr int Tt    = 2048;
constexpr int INt   = 128;
constexpr int Ht    = 256;
constexpr int OUTt  = 8;
constexpr int TT    = 32;           // time tile
constexpr int NTILE = 64;

union Frag {
  s16x8 s;
  bf16x8 b;
  u32x4 u;
};

DEVFN unsigned short f2bf(float f) {
  unsigned int u = __builtin_bit_cast(unsigned int, f);
  u += 0x7fffu + ((u >> 16) & 1u);   // round-to-nearest-even
  return (unsigned short)(u >> 16);
}

DEVFN unsigned int pack2(float lo, float hi) {
  return (unsigned int)f2bf(lo) | ((unsigned int)f2bf(hi) << 16);
}

typedef __attribute__((address_space(3))) unsigned int lds_u32;
typedef const __attribute__((address_space(1))) unsigned int glb_u32;

// HBM -> LDS DMA, 16B/lane, LDS dest = uniform base + lane*16 (linear).
DEVFN void dma16(const float* g, const float* l) {
  __builtin_amdgcn_global_load_lds((glb_u32*)(uintptr_t)g,
                                   (lds_u32*)(unsigned int)(uintptr_t)l,
                                   16, 0, 0);
}

__global__
__attribute__((amdgpu_flat_work_group_size(1024, 1024)))
void sfnn_fused(
    const float* __restrict__ x, const float* __restrict__ Wb,
    const float* __restrict__ bb, const float* __restrict__ Wo,
    const float* __restrict__ bo, const float* __restrict__ tau_m,
    const float* __restrict__ tau_n, float* __restrict__ out)
{
  const int b    = blockIdx.x;
  const int tid  = threadIdx.x;
  const int lane = tid & 63;
  const int w    = tid >> 6;          // wave id 0..15
  const int l16  = lane & 15;
  const int lhi  = lane >> 4;

  // Roles: w0-3 SCAN | w4,5 PROJ | w6-13 GEMM (32t x 32h each) | w14,15 DMA-stage
  const int hg  = w - 6;              // GEMM strip: cols [32hg, 32hg+32)
  const int sw2 = w - 14;             // stager wave: 0,1

  // LDS: 32K Xraw[2] + 16K Xb[2] + 64K DfT[2] + 32K Mb[2] + 8K WoT = 152KB
  __shared__ __align__(16) float          Xraw[2][TT * INt];   // DMA dest, linear f32
  __shared__ __align__(16) unsigned char  Xb[2][TT * 256];     // bf16 x, swizzled
  __shared__ __align__(16) float          DfT[2][Ht * TT];     // D^T f32 [h][t], swz
  __shared__ __align__(16) unsigned short Mb[2][TT * Ht];      // m bf16 [t][h], swz
  __shared__ __align__(16) unsigned short WoT[16 * Ht];        // Wo^T bf16 [j][k], swz

  // ---- stage WoT: [j][k] bf16, rows j>=8 zero (r6-verbatim) ----
  {
    const int j  = w;
    const int k0 = 4 * (tid & 63);
    float v0 = 0.f, v1 = 0.f, v2 = 0.f, v3 = 0.f;
    if (j < OUTt) {
      v0 = Wo[(k0 + 0) * OUTt + j]; v1 = Wo[(k0 + 1) * OUTt + j];
      v2 = Wo[(k0 + 2) * OUTt + j]; v3 = Wo[(k0 + 3) * OUTt + j];
    }
    unsigned long long pk = (unsigned long long)pack2(v0, v1) |
                            ((unsigned long long)pack2(v2, v3) << 32);
    *(unsigned long long*)(&WoT[j * 256 + (k0 ^ ((j & 7) << 3))]) = pk;
  }

  // ---- branch weights: GEMM waves 6-13 own h in [32hg, 32hg+32) (r14) ----
  Frag Wf[2][4];                      // 32 VGPRs, GEMM waves only
  if (w >= 6 && w < 14) {
    #pragma unroll
    for (int nh = 0; nh < 2; ++nh) {
      const int h = 32 * hg + 16 * nh + l16;
      const int n = h >> 6, s = h & 63;
      #pragma unroll
      for (int ks = 0; ks < 4; ++ks) {
        #pragma unroll
        for (int j = 0; j < 8; ++j) {
          const int i = 32 * ks + 8 * lhi + j;
          Wf[nh][ks].s[j] = (short)f2bf(Wb[(n * 128 + i) * 64 + s]);
        }
      }
    }
  }

  // ---- scan params: threads 0..255 (channel = tid), guarded ----
  float beta = 0.f, alpha = 0.f, omb = 0.f, oma = 0.f, bbh = 0.f;
  if (tid < 256) {
    beta  = 1.f / (1.f + expf(-tau_n[tid]));
    alpha = 1.f / (1.f + expf(-tau_m[tid]));
    omb   = 1.f - beta;
    oma   = 1.f - alpha;
    bbh   = bb[tid];
  }
  float bo_l = 0.f;
  if (w == 4 || w == 5) bo_l = (l16 < OUTt) ? bo[l16] : 0.f;

  const float* xb   = x   + (size_t)b * Tt * INt;
  float*       outb = out + (size_t)b * Tt * OUTt;

  float c_s = 0.f, m_s = 0.f;          // scan state (threads 0..255)
  f32x4 dacc[2][2];                    // [tt][nh], GEMM waves (within-phase)

  #define BAR() do {                                                       \
    asm volatile("s_waitcnt lgkmcnt(0)" ::: "memory");                     \
    __builtin_amdgcn_s_barrier();                                          \
  } while (0)

  #define WAITVM(N) do {                                                   \
    asm volatile("s_waitcnt vmcnt(" #N ")" ::: "memory");                  \
    __builtin_amdgcn_sched_barrier(0);                                     \
  } while (0)

  // stager waves 14,15: wave DMAs its own 8 chunks of 1KB (r8 pattern)
  #define ISSUE_DMA(TILE) do {                                             \
    const int _bi = (TILE) & 1;                                            \
    const float* _gs = xb + (size_t)(TILE) * (TT * INt);                   \
    _Pragma("unroll")                                                      \
    for (int q = 0; q < 8; ++q) {                                          \
      const int c = 8 * sw2 + q;                                           \
      dma16(_gs + c * 256 + lane * 4, &Xraw[_bi][c * 256]);                \
    }                                                                      \
  } while (0)

  // wave converts EXACTLY the chunks it DMA'd (own vmcnt covers them).
  // chunk c = floats [256c,256c+256) = t rows 2c,2c+1; lane reads f32x4 at
  // 256c+4*lane -> t = 2c+(lane>>5), kb = 8*(lane&31)  (r8-verified)
  #define CONVERT(TILE) do {                                               \
    const int _bi = (TILE) & 1;                                            \
    const int kb  = 8 * (lane & 31);                                       \
    _Pragma("unroll")                                                      \
    for (int q = 0; q < 8; ++q) {                                          \
      const int c = 8 * sw2 + q;                                           \
      const int t = 2 * c + (lane >> 5);                                   \
      f32x4 v = *(const f32x4*)(&Xraw[_bi][256 * c + 4 * lane]);           \
      unsigned long long pk = (unsigned long long)pack2(v[0], v[1]) |      \
            ((unsigned long long)pack2(v[2], v[3]) << 32);                 \
      *(unsigned long long*)(&Xb[_bi][t * 256 + (kb ^ ((t & 7) << 4))]) = pk; \
    }                                                                      \
  } while (0)

  // GEMM waves 6-13: D[t 0..32)[h 32hg..+32), K=128 (r14-verified loops)
  #define GEMM(BUF) do {                                                   \
    _Pragma("unroll")                                                      \
    for (int tt = 0; tt < 2; ++tt) {                                       \
      _Pragma("unroll")                                                    \
      for (int nh = 0; nh < 2; ++nh) dacc[tt][nh] = f32x4{0.f,0.f,0.f,0.f};\
      const int row = 16 * tt + l16;                                       \
      const int rs = row * 256, sw = (row & 7) << 4;                       \
      _Pragma("unroll")                                                    \
      for (int ks = 0; ks < 4; ++ks) {                                     \
        Frag a;                                                            \
        a.u = *(const u32x4*)(&Xb[BUF][rs + ((64 * ks + 16 * lhi) ^ sw)]); \
        _Pragma("unroll")                                                  \
        for (int nh = 0; nh < 2; ++nh)                                     \
          dacc[tt][nh] = __builtin_amdgcn_mfma_f32_16x16x32_bf16(          \
              a.b, Wf[nh][ks].b, dacc[tt][nh], 0, 0, 0);                   \
      }                                                                    \
    }                                                                      \
  } while (0)

  // dacc -> DfT[h][t]: rows 128B; t-quad qi = 4tt+lhi, slot qi^(h&7)
  #define WRITEDF(BUF) do {                                                \
    _Pragma("unroll")                                                      \
    for (int tt = 0; tt < 2; ++tt) {                                       \
      const int qi = 4 * tt + lhi;                                         \
      _Pragma("unroll")                                                    \
      for (int nh = 0; nh < 2; ++nh) {                                     \
        const int h = 32 * hg + 16 * nh + l16;                             \
        *(f32x4*)(&DfT[BUF][h * 32 + ((qi ^ (h & 7)) << 2)]) = dacc[tt][nh]; \
      }                                                                    \
    }                                                                      \
  } while (0)

  // scan threads 0..255: own-row b128 reads (slot q^h7) + serial EMA + Mb b16
  #define SCAN(BUF) do {                                                   \
    if (tid < 256) {                                                       \
      const int hb = tid * 32, h7 = tid & 7;                               \
      _Pragma("unroll")                                                    \
      for (int g = 0; g < 2; ++g) {                                        \
        f32x4 dv[4];                                                       \
        _Pragma("unroll")                                                  \
        for (int q = 0; q < 4; ++q)                                        \
          dv[q] = *(const f32x4*)(&DfT[BUF][hb + (((4 * g + q) ^ h7) << 2)]); \
        _Pragma("unroll")                                                  \
        for (int q = 0; q < 4; ++q)                                        \
          _Pragma("unroll")                                                \
          for (int r = 0; r < 4; ++r) {                                    \
            const int t = 16 * g + 4 * q + r;                              \
            const float d = dv[q][r] + bbh;                                \
            c_s = fmaf(beta, c_s, omb * d);                                \
            m_s = fmaf(alpha, m_s, oma * c_s);                             \
            Mb[BUF][t * 256 + (tid ^ ((t & 7) << 3))] = f2bf(m_s);         \
          }                                                                \
      }                                                                    \
    }                                                                      \
  } while (0)

  // proj waves 4,5: rows [16(w-4),+16), full K=256 (r6-verbatim)
  #define PROJ(TI, BUF) do {                                               \
    const int tp = w - 4;                                                  \
    const int trow = 16 * tp + l16;                                        \
    const int mrb = trow * 256, msw = (trow & 7) << 3;                     \
    const int wrb = l16 * 256,  wsw = (l16 & 7) << 3;                      \
    f32x4 p = f32x4{0.f, 0.f, 0.f, 0.f};                                   \
    _Pragma("unroll")                                                      \
    for (int ks = 0; ks < 8; ++ks) {                                       \
      const int k0 = 32 * ks + 8 * lhi;                                    \
      Frag ma, wo;                                                         \
      ma.u = *(const u32x4*)(&Mb[BUF][mrb + (k0 ^ msw)]);                  \
      wo.u = *(const u32x4*)(&WoT[wrb + (k0 ^ wsw)]);                      \
      p = __builtin_amdgcn_mfma_f32_16x16x32_bf16(ma.b, wo.b, p, 0, 0, 0); \
    }                                                                      \
    if (l16 < OUTt) {                                                      \
      _Pragma("unroll")                                                    \
      for (int r = 0; r < 4; ++r) {                                        \
        const int t = 16 * tp + 4 * lhi + r;                               \
        outb[(size_t)((TI) * TT + t) * OUTt + l16] =                       \
            1.f / (1.f + __expf(-(p[r] + bo_l)));                          \
      }                                                                    \
    }                                                                      \
  } while (0)

  // ---- single-phase iteration: one barrier; roles fully disjoint ----
  // iter I: GEMM(I) Xb[I&1]->DfT[I&1] | SCAN(I-1) | PROJ(I-2) Mb[I&1]
  //         | w14,15: DMA(I+2)->Xraw[I&1], WAITVM, CONVERT(I+1)->Xb[(I+1)&1]
  #define ITER(I, DOG, DOS, DOP, ISS_STMT, WAIT_STMT, CVT_STMT) do {       \
    if (w < 4)        { if (DOS) SCAN(((I) - 1) & 1); }                    \
    else if (w < 6)   { if (DOP) PROJ((I) - 2, (I) & 1); }                 \
    else if (w < 14)  { if (DOG) { GEMM((I) & 1); WRITEDF((I) & 1); } }    \
    else              { ISS_STMT; WAIT_STMT; CVT_STMT; }                   \
    BAR();                                                                 \
  } while (0)

  // ---------------- prologue ----------------
  if (w >= 14) {
    ISSUE_DMA(0);
    ISSUE_DMA(1);                      // 16 outstanding (own)
    WAITVM(8);                         // own tile-0 chunks landed
    CONVERT(0);                        // Xb[0]
  }
  BAR();

  // ---------------- pipeline: I = 0..65 ----------------
  ITER(0, 1, 0, 0, ISSUE_DMA(2), WAITVM(8), CONVERT(1));
  ITER(1, 1, 1, 0, ISSUE_DMA(3), WAITVM(8), CONVERT(2));
  for (int I = 2; I <= 61; ++I)
    ITER(I, 1, 1, 1, ISSUE_DMA(I + 2), WAITVM(8), CONVERT(I + 1));
  ITER(62, 1, 1, 1, (void)0, WAITVM(0), CONVERT(63));
  ITER(63, 1, 1, 1, (void)0, (void)0, (void)0);
  ITER(64, 0, 1, 1, (void)0, (void)0, (void)0);   // SCAN(63), PROJ(62)
  ITER(65, 0, 0, 1, (void)0, (void)0, (void)0);   // PROJ(63)

  #undef ISSUE_DMA
  #undef CONVERT
  #undef GEMM
  #undef WRITEDF
  #undef SCAN
  #undef PROJ
  #undef ITER
  #undef BAR
  #undef WAITVM
}

extern "C" void kernel_launch(void* const* d_in, const int* in_sizes, int n_in,
                              void* d_out, int out_size, void* d_ws, size_t ws_size,
                              hipStream_t stream) {
  const float* x     = (const float*)d_in[0];
  const float* Wb    = (const float*)d_in[1];
  const float* bb    = (const float*)d_in[2];
  const float* Wo    = (const float*)d_in[3];
  const float* bo    = (const float*)d_in[4];
  const float* tau_m = (const float*)d_in[5];
  const float* tau_n = (const float*)d_in[6];
  float* out = (float*)d_out;

  sfnn_fused<<<dim3(256), dim3(1024), 0, stream>>>(x, Wb, bb, Wo, bo, tau_m, tau_n, out);
}

// Round 19
// 99.863 us; speedup vs baseline: 1.1713x; 1.1713x over previous
//
#include <hip/hip_runtime.h>
#include <hip/hip_bf16.h>
#include <math.h>

#define DEVFN __device__ __forceinline__

typedef __attribute__((ext_vector_type(8))) __bf16 bf16x8;
typedef __attribute__((ext_vector_type(8))) short s16x8;
typedef __attribute__((ext_vector_type(4))) float f32x4;
typedef __attribute__((ext_vector_type(4))) unsigned int u32x4;

constexpr int Tt    = 2048;
constexpr int INt   = 128;
constexpr int Ht    = 256;
constexpr int OUTt  = 8;
constexpr int TT    = 32;           // time tile
constexpr int NTILE = 64;

union Frag {
  s16x8 s;
  bf16x8 b;
  u32x4 u;
};

DEVFN unsigned short f2bf(float f) {
  unsigned int u = __builtin_bit_cast(unsigned int, f);
  u += 0x7fffu + ((u >> 16) & 1u);   // round-to-nearest-even
  return (unsigned short)(u >> 16);
}

DEVFN unsigned int pack2(float lo, float hi) {
  return (unsigned int)f2bf(lo) | ((unsigned int)f2bf(hi) << 16);
}

__global__
__attribute__((amdgpu_flat_work_group_size(1024, 1024)))
void sfnn_fused(
    const float* __restrict__ x, const float* __restrict__ Wb,
    const float* __restrict__ bb, const float* __restrict__ Wo,
    const float* __restrict__ bo, const float* __restrict__ tau_m,
    const float* __restrict__ tau_n, float* __restrict__ out)
{
  const int b    = blockIdx.x;
  const int tid  = threadIdx.x;
  const int lane = tid & 63;
  const int w    = tid >> 6;          // wave id 0..15
  const int l16  = lane & 15;
  const int lhi  = lane >> 4;
  const int sid  = tid - 512;         // stager index (waves 8-15)

  // GEMM decomposition: 16 waves x (16t x 32h) covering 32t x 256h
  const int tg = w >> 3;              // t-half: rows [16tg, 16tg+16)
  const int hg = w & 7;               // h-strip: cols [32hg, 32hg+32)

  // LDS: 24KB Xb[3] + 64KB DfT[2] + 32KB Mb[2] + 8KB WoT = 128KB
  __shared__ __align__(16) unsigned char  Xb[3][TT * 256];      // bf16 x, swizzled
  __shared__ __align__(16) float          DfT[2][Ht * TT];      // D^T f32 [h][t], swz
  __shared__ __align__(16) unsigned short Mb[2][TT * Ht];       // m bf16 [t][h], swz
  __shared__ __align__(16) unsigned short WoT[16 * Ht];         // Wo^T bf16 [j][k], swz

  // ---- stage WoT: [j][k] bf16, rows j>=8 zero (r6-verbatim) ----
  {
    const int j  = w;
    const int k0 = 4 * (tid & 63);
    float v0 = 0.f, v1 = 0.f, v2 = 0.f, v3 = 0.f;
    if (j < OUTt) {
      v0 = Wo[(k0 + 0) * OUTt + j]; v1 = Wo[(k0 + 1) * OUTt + j];
      v2 = Wo[(k0 + 2) * OUTt + j]; v3 = Wo[(k0 + 3) * OUTt + j];
    }
    unsigned long long pk = (unsigned long long)pack2(v0, v1) |
                            ((unsigned long long)pack2(v2, v3) << 32);
    *(unsigned long long*)(&WoT[j * 256 + (k0 ^ ((j & 7) << 3))]) = pk;
  }

  // ---- branch weights: wave owns h in [32hg, 32hg+32) (r14-verified) ----
  Frag Wf[2][4];                      // [16-col half][k-step] = 32 VGPRs
  #pragma unroll
  for (int nh = 0; nh < 2; ++nh) {
    const int h = 32 * hg + 16 * nh + l16;
    const int n = h >> 6, s = h & 63;
    #pragma unroll
    for (int ks = 0; ks < 4; ++ks) {
      #pragma unroll
      for (int j = 0; j < 8; ++j) {
        const int i = 32 * ks + 8 * lhi + j;
        Wf[nh][ks].s[j] = (short)f2bf(Wb[(n * 128 + i) * 64 + s]);
      }
    }
  }

  // ---- scan params: threads 0..255 (channel = tid), guarded ----
  float beta = 0.f, alpha = 0.f, omb = 0.f, oma = 0.f, bbh = 0.f;
  if (tid < 256) {
    beta  = 1.f / (1.f + expf(-tau_n[tid]));
    alpha = 1.f / (1.f + expf(-tau_m[tid]));
    omb   = 1.f - beta;
    oma   = 1.f - alpha;
    bbh   = bb[tid];
  }
  float bo_l = 0.f;
  if (w == 4 || w == 5) bo_l = (l16 < OUTt) ? bo[l16] : 0.f;

  const float* xb   = x   + (size_t)b * Tt * INt;
  float*       outb = out + (size_t)b * Tt * OUTt;

  float c_s = 0.f, m_s = 0.f;          // scan state (threads 0..255)
  f32x4 dacc[2];                       // [nh] (within-phase only)
  f32x4 QA0, QA1, QB0, QB1;            // TWO stager prefetch sets (hazard-free)

  #define BAR() do {                                                       \
    asm volatile("s_waitcnt lgkmcnt(0)" ::: "memory");                     \
    __builtin_amdgcn_s_barrier();                                          \
  } while (0)

  #define WAITVM(N) do {                                                   \
    asm volatile("s_waitcnt vmcnt(" #N ")" ::: "memory");                  \
    __builtin_amdgcn_sched_barrier(0);                                     \
  } while (0)

  // stager waves 8-15: tile = 4096 floats; 2 x 16B asm-pinned loads
  #define ISSUE(TILE, Q0, Q1) do {                                         \
    const float* _p = xb + (size_t)(TILE) * (TT * INt) + 4 * (size_t)sid;  \
    asm volatile("global_load_dwordx4 %0, %1, off" : "=&v"(Q0) : "v"(_p));        \
    asm volatile("global_load_dwordx4 %0, %1, off" : "=&v"(Q1) : "v"(_p + 2048)); \
  } while (0)

  // write staged rounds: float f = 2048q + 4sid -> t = 16q + (sid>>5)
  #define STAGEWR(BUF, Q0, Q1) do {                                        \
    const int kb = 8 * (sid & 31);                                         \
    {                                                                      \
      const int t = (sid >> 5);                                            \
      unsigned long long pk = (unsigned long long)pack2(Q0.x, Q0.y) |      \
            ((unsigned long long)pack2(Q0.z, Q0.w) << 32);                 \
      *(unsigned long long*)(&Xb[BUF][t * 256 + (kb ^ ((t & 7) << 4))]) = pk; \
    }                                                                      \
    {                                                                      \
      const int t = 16 + (sid >> 5);                                       \
      unsigned long long pk = (unsigned long long)pack2(Q1.x, Q1.y) |      \
            ((unsigned long long)pack2(Q1.z, Q1.w) << 32);                 \
      *(unsigned long long*)(&Xb[BUF][t * 256 + (kb ^ ((t & 7) << 4))]) = pk; \
    }                                                                      \
  } while (0)

  // GEMM: wave computes D[16tg..+16)[32hg..+32), K=128; 4 b128 reads + 8 MFMA
  #define GEMM(BUF) do {                                                   \
    dacc[0] = f32x4{0.f, 0.f, 0.f, 0.f};                                   \
    dacc[1] = f32x4{0.f, 0.f, 0.f, 0.f};                                   \
    const int row = 16 * tg + l16;                                         \
    const int rs = row * 256, sw = (row & 7) << 4;                         \
    _Pragma("unroll")                                                      \
    for (int ks = 0; ks < 4; ++ks) {                                       \
      Frag a;                                                              \
      a.u = *(const u32x4*)(&Xb[BUF][rs + ((64 * ks + 16 * lhi) ^ sw)]);   \
      dacc[0] = __builtin_amdgcn_mfma_f32_16x16x32_bf16(                   \
          a.b, Wf[0][ks].b, dacc[0], 0, 0, 0);                             \
      dacc[1] = __builtin_amdgcn_mfma_f32_16x16x32_bf16(                   \
          a.b, Wf[1][ks].b, dacc[1], 0, 0, 0);                             \
    }                                                                      \
  } while (0)

  // dacc -> DfT[h][t]: rows 128B (32 f32); t-quad qi = 4tg+lhi, slot qi^(h&7)
  #define WRITEDF(BUF) do {                                                \
    const int qi = 4 * tg + lhi;                                           \
    _Pragma("unroll")                                                      \
    for (int nh = 0; nh < 2; ++nh) {                                       \
      const int h = 32 * hg + 16 * nh + l16;                               \
      *(f32x4*)(&DfT[BUF][h * 32 + ((qi ^ (h & 7)) << 2)]) = dacc[nh];     \
    }                                                                      \
  } while (0)

  // scan threads 0..255: own-row b128 reads (slot q^h7) + serial EMA + Mb b16
  #define SCAN(BUF) do {                                                   \
    if (tid < 256) {                                                       \
      const int hb = tid * 32, h7 = tid & 7;                               \
      _Pragma("unroll")                                                    \
      for (int g = 0; g < 2; ++g) {                                        \
        f32x4 dv[4];                                                       \
        _Pragma("unroll")                                                  \
        for (int q = 0; q < 4; ++q)                                        \
          dv[q] = *(const f32x4*)(&DfT[BUF][hb + (((4 * g + q) ^ h7) << 2)]); \
        _Pragma("unroll")                                                  \
        for (int q = 0; q < 4; ++q)                                        \
          _Pragma("unroll")                                                \
          for (int r = 0; r < 4; ++r) {                                    \
            const int t = 16 * g + 4 * q + r;                              \
            const float d = dv[q][r] + bbh;                                \
            c_s = fmaf(beta, c_s, omb * d);                                \
            m_s = fmaf(alpha, m_s, oma * c_s);                             \
            Mb[BUF][t * 256 + (tid ^ ((t & 7) << 3))] = f2bf(m_s);         \
          }                                                                \
      }                                                                    \
    }                                                                      \
  } while (0)

  // proj waves 4,5: rows [16(w-4),+16), full K=256 (r6-verbatim)
  #define PROJ(TI, BUF) do {                                               \
    const int tp = w - 4;                                                  \
    const int trow = 16 * tp + l16;                                        \
    const int mrb = trow * 256, msw = (trow & 7) << 3;                     \
    const int wrb = l16 * 256,  wsw = (l16 & 7) << 3;                      \
    f32x4 p = f32x4{0.f, 0.f, 0.f, 0.f};                                   \
    _Pragma("unroll")                                                      \
    for (int ks = 0; ks < 8; ++ks) {                                       \
      const int k0 = 32 * ks + 8 * lhi;                                    \
      Frag ma, wo;                                                         \
      ma.u = *(const u32x4*)(&Mb[BUF][mrb + (k0 ^ msw)]);                  \
      wo.u = *(const u32x4*)(&WoT[wrb + (k0 ^ wsw)]);                      \
      p = __builtin_amdgcn_mfma_f32_16x16x32_bf16(ma.b, wo.b, p, 0, 0, 0); \
    }                                                                      \
    if (l16 < OUTt) {                                                      \
      _Pragma("unroll")                                                    \
      for (int r = 0; r < 4; ++r) {                                        \
        const int t = 16 * tp + 4 * lhi + r;                               \
        outb[(size_t)((TI) * TT + t) * OUTt + l16] =                       \
            1.f / (1.f + __expf(-(p[r] + bo_l)));                          \
      }                                                                    \
    }                                                                      \
  } while (0)

  // ---- single-phase iteration, 1 barrier; QA/QB alternate (hazard-free) ----
  // r19 delta: scan waves (w0-3) run SCAN FIRST, then GEMM -- the serial EMA
  // chain starts ~200cy earlier and GEMM's independent MFMAs fill its stalls.
  #define ITER_EV(I, DOG, DOS, DOP, DOISS, DOSTG, WN) do {                 \
    if ((DOISS) && w >= 8) ISSUE((I) + 2, QA0, QA1);                       \
    if (w < 4) {                                                           \
      if (DOS) SCAN(((I) - 1) & 1);                                        \
      if (DOG) { GEMM((I) % 3); WRITEDF((I) & 1); }                        \
    } else {                                                               \
      if (DOG) { GEMM((I) % 3); WRITEDF((I) & 1); }                        \
      if ((DOP) && (w == 4 || w == 5)) PROJ((I) - 2, (I) & 1);             \
      if ((DOSTG) && w >= 8) { WAITVM(WN); STAGEWR(((I) + 1) % 3, QB0, QB1); } \
    }                                                                      \
    BAR();                                                                 \
  } while (0)

  #define ITER_OD(I, DOG, DOS, DOP, DOISS, DOSTG, WN) do {                 \
    if ((DOISS) && w >= 8) ISSUE((I) + 2, QB0, QB1);                       \
    if (w < 4) {                                                           \
      if (DOS) SCAN(((I) - 1) & 1);                                        \
      if (DOG) { GEMM((I) % 3); WRITEDF((I) & 1); }                        \
    } else {                                                               \
      if (DOG) { GEMM((I) % 3); WRITEDF((I) & 1); }                        \
      if ((DOP) && (w == 4 || w == 5)) PROJ((I) - 2, (I) & 1);             \
      if ((DOSTG) && w >= 8) { WAITVM(WN); STAGEWR(((I) + 1) % 3, QA0, QA1); } \
    }                                                                      \
    BAR();                                                                 \
  } while (0)

  // ---------------- prologue: stage tile 0 (A), issue tile 1 (B) ----------
  if (w >= 8) {
    ISSUE(0, QA0, QA1);
    WAITVM(0);
    STAGEWR(0, QA0, QA1);
    ISSUE(1, QB0, QB1);                // in flight across barrier
  }
  BAR();

  // ---------------- pipeline: I = 0..65 ----------------
  ITER_EV(0, 1, 0, 0, 1, 1, 2);        // issue 2->A, stage 1 (B)
  ITER_OD(1, 1, 1, 0, 1, 1, 2);        // issue 3->B, stage 2 (A)
  for (int jj = 1; jj <= 30; ++jj) {
    ITER_EV(2 * jj,     1, 1, 1, 1, 1, 2);
    ITER_OD(2 * jj + 1, 1, 1, 1, 1, 1, 2);
  }
  ITER_EV(62, 1, 1, 1, 0, 1, 0);       // drain, stage 63 (B)
  ITER_OD(63, 1, 1, 1, 0, 0, 0);
  ITER_EV(64, 0, 1, 1, 0, 0, 0);       // SCAN(63), PROJ(62)
  ITER_OD(65, 0, 0, 1, 0, 0, 0);       // PROJ(63)

  #undef ISSUE
  #undef STAGEWR
  #undef GEMM
  #undef WRITEDF
  #undef SCAN
  #undef PROJ
  #undef ITER_EV
  #undef ITER_OD
  #undef BAR
  #undef WAITVM
}

extern "C" void kernel_launch(void* const* d_in, const int* in_sizes, int n_in,
                              void* d_out, int out_size, void* d_ws, size_t ws_size,
                              hipStream_t stream) {
  const float* x     = (const float*)d_in[0];
  const float* Wb    = (const float*)d_in[1];
  const float* bb    = (const float*)d_in[2];
  const float* Wo    = (const float*)d_in[3];
  const float* bo    = (const float*)d_in[4];
  const float* tau_m = (const float*)d_in[5];
  const float* tau_n = (const float*)d_in[6];
  float* out = (float*)d_out;

  sfnn_fused<<<dim3(256), dim3(1024), 0, stream>>>(x, Wb, bb, Wo, bo, tau_m, tau_n, out);
}